// Round 8
// baseline (3547.465 us; speedup 1.0000x reference)
//
#include <hip/hip_runtime.h>

// Problem constants (B=4, TT=16, T=8, C=3, H=W=256, STRIDE=8, Fd=128, fh=fw=32)
#define FD 128
#define HWP 1024
#define FRAME_ELEMS (HWP * FD)     // 131072 floats per frame (seq layout [pixel][ch])
#define MAT 1048576                 // 1024*1024
#define TEMP_INV 14.285714285714286f
static constexpr int PATCH = 192;   // 3*8*8

// ---------------------------------------------------------------------------
// Kernel 0: transpose conv weights [128][192] -> [192][128] for coalesced reads
// ---------------------------------------------------------------------------
__global__ __launch_bounds__(256) void transpose_w_kernel(
    const float* __restrict__ w, float* __restrict__ wt)
{
    int idx = blockIdx.x * 256 + threadIdx.x;
    if (idx < FD * PATCH) {
        int o = idx / PATCH, k = idx - o * PATCH;
        wt[k * FD + o] = w[idx];
    }
}

// ---------------------------------------------------------------------------
// Kernel 1: patch-embed conv (stride-8 8x8, VALID) + ReLU + channel l2norm.
// Output feat_seq[frame][pixel][ch], frame = b*16 + t.
// grid (128 pixel-groups of 8, 64 frames), block 128 (one thread per channel).
// ---------------------------------------------------------------------------
__global__ __launch_bounds__(128) void encoder_kernel(
    const float* __restrict__ x, const float* __restrict__ wt,
    float* __restrict__ feat)
{
    const int frame = blockIdx.y;
    const int pg0 = blockIdx.x * 8;
    const int c = threadIdx.x;

    __shared__ float patch[8][PATCH];
    __shared__ float part[8][2];

    for (int idx = c; idx < 8 * PATCH; idx += 128) {
        int p = idx / PATCH, k = idx - p * PATCH;
        int pg = pg0 + p;
        int oy = pg >> 5, ox = pg & 31;
        int ci = k >> 6, r = k & 63;
        int ky = r >> 3, kx = r & 7;
        patch[p][k] = x[(size_t)(((frame * 3 + ci) << 8) + oy * 8 + ky) * 256
                        + ox * 8 + kx];
    }
    __syncthreads();

    float acc[8] = {0.f, 0.f, 0.f, 0.f, 0.f, 0.f, 0.f, 0.f};
    for (int k = 0; k < PATCH; ++k) {
        float wv = wt[k * FD + c];   // coalesced, L2-resident (98 KB)
#pragma unroll
        for (int p = 0; p < 8; ++p) acc[p] = fmaf(wv, patch[p][k], acc[p]);
    }
#pragma unroll
    for (int p = 0; p < 8; ++p) acc[p] = fmaxf(acc[p], 0.f);

    const int lane = c & 63, wid = c >> 6;
#pragma unroll
    for (int p = 0; p < 8; ++p) {
        float s = acc[p] * acc[p];
#pragma unroll
        for (int off = 32; off > 0; off >>= 1) s += __shfl_xor(s, off, 64);
        if (lane == 0) part[p][wid] = s;
    }
    __syncthreads();

    float* out = feat + (size_t)frame * FRAME_ELEMS + (size_t)pg0 * FD + c;
#pragma unroll
    for (int p = 0; p < 8; ++p) {
        float nrm = fmaxf(sqrtf(part[p][0] + part[p][1]), 1e-12f);
        out[(size_t)p * FD] = acc[p] / nrm;
    }
}

// ---------------------------------------------------------------------------
// Kernel 2: affine grid + bilinear grid-sample (zero pad OOB) + channel l2norm.
// fa[n=(b*8+t)][pixel][ch].  grid (1024 pixels, 32 n), block 128.
// ---------------------------------------------------------------------------
__global__ __launch_bounds__(128) void sample_kernel(
    const float* __restrict__ feat, const float* __restrict__ aff,
    float* __restrict__ fa)
{
    const int p = blockIdx.x;
    const int n = blockIdx.y;
    const int c = threadIdx.x;
    const int b = n >> 3, t = n & 7;
    const float* th = aff + b * 6;
    const int oy = p >> 5, ox = p & 31;
    const float xs = -1.f + (2.f / 31.f) * (float)ox;
    const float ys = -1.f + (2.f / 31.f) * (float)oy;
    const float gx = th[0] * xs + th[1] * ys + th[2];
    const float gy = th[3] * xs + th[4] * ys + th[5];
    const float ix = (gx + 1.f) * 0.5f * 31.f;
    const float iy = (gy + 1.f) * 0.5f * 31.f;
    const float x0 = floorf(ix), y0 = floorf(iy);
    const float x1 = x0 + 1.f, y1 = y0 + 1.f;
    const float wx1 = ix - x0, wx0 = 1.f - wx1;
    const float wy1 = iy - y0, wy0 = 1.f - wy1;

    const float* fr = feat + (size_t)(b * 16 + t) * FRAME_ELEMS;

    float yys[4] = {y0, y0, y1, y1};
    float xxs[4] = {x0, x1, x0, x1};
    float wts[4] = {wy0 * wx0, wy0 * wx1, wy1 * wx0, wy1 * wx1};
    float v = 0.f;
#pragma unroll
    for (int q = 0; q < 4; ++q) {
        float yy = yys[q], xx = xxs[q];
        bool inb = (xx >= 0.f) && (xx <= 31.f) && (yy >= 0.f) && (yy <= 31.f);
        int yc = (int)fminf(fmaxf(yy, 0.f), 31.f);
        int xc = (int)fminf(fmaxf(xx, 0.f), 31.f);
        v += fr[(size_t)(yc * 32 + xc) * FD + c] * (inb ? wts[q] : 0.f);
    }

    __shared__ float part[2];
    float s = v * v;
#pragma unroll
    for (int off = 32; off > 0; off >>= 1) s += __shfl_xor(s, off, 64);
    const int lane = c & 63, wid = c >> 6;
    if (lane == 0) part[wid] = s;
    __syncthreads();
    float nrm = fmaxf(sqrtf(part[0] + part[1]), 1e-12f);
    fa[(size_t)n * FRAME_ELEMS + (size_t)p * FD + c] = v / nrm;
}

// ---------------------------------------------------------------------------
// Kernel 3: score GEMM C = X @ Y^T, X,Y 1024x128 row-major, C 1024x1024.
// Batched over grid.z (batch b): X = Xb + z*sX, Y = Yb + z*sY, C = Ob + z*MAT.
// 64x64 tile, 4x4 micro, BK=16, k-major LDS staging (stride 68).
// grid dim3(16,16,4) = 1024 blocks = 4 blocks/CU.
// ---------------------------------------------------------------------------
__global__ __launch_bounds__(256) void gemm_nt_score(
    const float* __restrict__ Xb, int sX,
    const float* __restrict__ Yb, int sY,
    float* __restrict__ Ob)
{
    const float* __restrict__ X = Xb + (size_t)blockIdx.z * (size_t)sX;
    const float* __restrict__ Y = Yb + (size_t)blockIdx.z * (size_t)sY;
    float* __restrict__ C = Ob + (size_t)blockIdx.z * (size_t)MAT;

    __shared__ float Xs[16][68];
    __shared__ float Ys[16][68];
    const int tid = threadIdx.x;
    const int bm = blockIdx.y * 64, bn = blockIdx.x * 64;
    const int tr = tid >> 4, tc = tid & 15;
    const int lm = tid >> 4, lk = tid & 15;
    float acc[4][4] = {};

    for (int k0 = 0; k0 < FD; k0 += 16) {
#pragma unroll
        for (int j = 0; j < 4; ++j)
            Xs[lk][lm + 16 * j] = X[(size_t)(bm + lm + 16 * j) * FD + k0 + lk];
#pragma unroll
        for (int j = 0; j < 4; ++j)
            Ys[lk][lm + 16 * j] = Y[(size_t)(bn + lm + 16 * j) * FD + k0 + lk];
        __syncthreads();
#pragma unroll
        for (int k = 0; k < 16; ++k) {
            float4 a4 = *(const float4*)&Xs[k][4 * tr];
            float4 b4 = *(const float4*)&Ys[k][4 * tc];
            float aa[4] = {a4.x, a4.y, a4.z, a4.w};
            float bb[4] = {b4.x, b4.y, b4.z, b4.w};
#pragma unroll
            for (int i = 0; i < 4; ++i)
#pragma unroll
                for (int j = 0; j < 4; ++j)
                    acc[i][j] = fmaf(aa[i], bb[j], acc[i][j]);
        }
        __syncthreads();
    }
#pragma unroll
    for (int i = 0; i < 4; ++i) {
        float4 st = {acc[i][0], acc[i][1], acc[i][2], acc[i][3]};
        *(float4*)&C[(size_t)(bm + 4 * tr + i) * HWP + bn + 4 * tc] = st;
    }
}

// ---------------------------------------------------------------------------
// Kernel 4: row softmax of s/TEMP, in place. One block per 1024-elem row.
// ---------------------------------------------------------------------------
__global__ __launch_bounds__(256) void softmax_kernel(float* __restrict__ s)
{
    float* __restrict__ r = s + (size_t)blockIdx.x * HWP;
    const int tid = threadIdx.x;
    const int lane = tid & 63, wid = tid >> 6;
    __shared__ float redm[4];
    __shared__ float reds[4];

    float4 v = ((const float4*)r)[tid];
    float m = fmaxf(fmaxf(v.x, v.y), fmaxf(v.z, v.w));
#pragma unroll
    for (int off = 32; off > 0; off >>= 1) m = fmaxf(m, __shfl_xor(m, off, 64));
    if (lane == 0) redm[wid] = m;
    __syncthreads();
    m = fmaxf(fmaxf(redm[0], redm[1]), fmaxf(redm[2], redm[3]));

    float e[4];
    e[0] = expf((v.x - m) * TEMP_INV);
    e[1] = expf((v.y - m) * TEMP_INV);
    e[2] = expf((v.z - m) * TEMP_INV);
    e[3] = expf((v.w - m) * TEMP_INV);
    float ss = e[0] + e[1] + e[2] + e[3];
#pragma unroll
    for (int off = 32; off > 0; off >>= 1) ss += __shfl_xor(ss, off, 64);
    if (lane == 0) reds[wid] = ss;
    __syncthreads();
    float inv = 1.f / (reds[0] + reds[1] + reds[2] + reds[3]);
    float4 o = {e[0] * inv, e[1] * inv, e[2] * inv, e[3] * inv};
    ((float4*)r)[tid] = o;
}

// ---------------------------------------------------------------------------
// Kernel 5: batched SGEMM C = A @ B, 1024x1024 row-major, batch on grid.z.
// 128x128 tile, 8x8 micro (split {4t, 64+4t}), BK=8, double-buffered LDS,
// one barrier/step, next-step global loads issued before compute.
// LDS traffic: 0.5 B/FMA -> VALU-bound, not LDS-BW-bound.
// ---------------------------------------------------------------------------
__global__ __launch_bounds__(256) void gemm_nn128(
    const float* __restrict__ Ab, int sA,
    const float* __restrict__ Bb, int sB,
    float* __restrict__ Cb, int sC)
{
    const float* __restrict__ A = Ab + (size_t)blockIdx.z * (size_t)sA;
    const float* __restrict__ B = Bb + (size_t)blockIdx.z * (size_t)sB;
    float* __restrict__ C = Cb + (size_t)blockIdx.z * (size_t)sC;

    __shared__ float As[2][8][128];   // k-major
    __shared__ float Bs[2][8][128];

    const int tid = threadIdx.x;
    const int ty = tid >> 4, tx = tid & 15;
    const int ar = tid >> 1;              // A staging row 0..127
    const int as = (tid & 1) << 2;        // A staging k-seg {0,4}
    const int bk = tid >> 5;              // B staging k 0..7
    const int bn4 = (tid & 31) << 2;      // B staging col {0,4,...,124}
    const int bm = blockIdx.y * 128, bn = blockIdx.x * 128;

    float4 areg = *(const float4*)&A[(size_t)(bm + ar) * 1024 + as];
    float4 breg = *(const float4*)&B[(size_t)bk * 1024 + bn + bn4];
    As[0][as + 0][ar] = areg.x;
    As[0][as + 1][ar] = areg.y;
    As[0][as + 2][ar] = areg.z;
    As[0][as + 3][ar] = areg.w;
    *(float4*)&Bs[0][bk][bn4] = breg;
    __syncthreads();

    float acc[8][8] = {};
    int cur = 0;

    for (int step = 0; step < 128; ++step) {
        if (step < 127) {
            const int k0 = (step + 1) * 8;
            areg = *(const float4*)&A[(size_t)(bm + ar) * 1024 + k0 + as];
            breg = *(const float4*)&B[(size_t)(k0 + bk) * 1024 + bn + bn4];
        }
#pragma unroll
        for (int k = 0; k < 8; ++k) {
            float4 a0 = *(const float4*)&As[cur][k][4 * ty];
            float4 a1 = *(const float4*)&As[cur][k][64 + 4 * ty];
            float4 b0 = *(const float4*)&Bs[cur][k][4 * tx];
            float4 b1 = *(const float4*)&Bs[cur][k][64 + 4 * tx];
            float av[8] = {a0.x, a0.y, a0.z, a0.w, a1.x, a1.y, a1.z, a1.w};
            float bv[8] = {b0.x, b0.y, b0.z, b0.w, b1.x, b1.y, b1.z, b1.w};
#pragma unroll
            for (int i = 0; i < 8; ++i)
#pragma unroll
                for (int j = 0; j < 8; ++j)
                    acc[i][j] = fmaf(av[i], bv[j], acc[i][j]);
        }
        if (step < 127) {
            const int nxt = cur ^ 1;
            As[nxt][as + 0][ar] = areg.x;
            As[nxt][as + 1][ar] = areg.y;
            As[nxt][as + 2][ar] = areg.z;
            As[nxt][as + 3][ar] = areg.w;
            *(float4*)&Bs[nxt][bk][bn4] = breg;
        }
        __syncthreads();
        cur ^= 1;
    }

#pragma unroll
    for (int i = 0; i < 4; ++i) {
        const size_t r0 = (size_t)(bm + 4 * ty + i) * HWP;
        const size_t r1 = (size_t)(bm + 64 + 4 * ty + i) * HWP;
        float4 s00 = {acc[i][0], acc[i][1], acc[i][2], acc[i][3]};
        float4 s01 = {acc[i][4], acc[i][5], acc[i][6], acc[i][7]};
        float4 s10 = {acc[4 + i][0], acc[4 + i][1], acc[4 + i][2], acc[4 + i][3]};
        float4 s11 = {acc[4 + i][4], acc[4 + i][5], acc[4 + i][6], acc[4 + i][7]};
        *(float4*)&C[r0 + bn + 4 * tx] = s00;
        *(float4*)&C[r0 + bn + 64 + 4 * tx] = s01;
        *(float4*)&C[r1 + bn + 4 * tx] = s10;
        *(float4*)&C[r1 + bn + 64 + 4 * tx] = s11;
    }
}

// ---------------------------------------------------------------------------
// Host launch.
// JIT-score design: score matrices are computed per scan step into a single
// reusable 4-mat buffer S (each score block is consumed exactly once).
// Peak workspace = 24 MAT + wt = 100.8 MB (was 420 MB; R3 run core-dumped,
// top hypothesis = ws overflow page fault).
// ---------------------------------------------------------------------------
extern "C" void kernel_launch(void* const* d_in, const int* in_sizes, int n_in,
                              void* d_out, int out_size, void* d_ws, size_t ws_size,
                              hipStream_t stream)
{
    const float* x     = (const float*)d_in[0];   // (4,16,3,256,256)
    const float* aff   = (const float*)d_in[1];   // (4,2,3)
    const float* convw = (const float*)d_in[2];   // (128,3,8,8)
    float* out = (float*)d_out;                   // (6,4,1024,1024)
    float* ws  = (float*)d_ws;

    // Guard: if ws is too small, bail out cleanly (output stays poisoned ->
    // loud absmax failure instead of a GPU page-fault abort).
    const size_t WS_NEED = ((size_t)24 * MAT + (size_t)FD * PATCH) * sizeof(float);
    if (ws_size < WS_NEED) return;

    // workspace layout (floats), MAT units
    float* feat = ws;                         // [ 0,  8) 64 frames
    float* fa   = ws + (size_t)8  * MAT;      // [ 8, 12) 32 warped frames
    float* S    = ws + (size_t)12 * MAT;      // [12, 16) reusable score block
    float* tm   = ws + (size_t)16 * MAT;      // [16, 20) scan carry
    float* tmp  = ws + (size_t)20 * MAT;      // [20, 24) scan temp
    float* wt   = ws + (size_t)24 * MAT;      // transposed conv weights

    const int sFF = 16 * FRAME_ELEMS;   // per-batch stride in feat (16 frames)
    const int sFA = 8 * FRAME_ELEMS;    // per-batch stride in fa (8 frames)

    transpose_w_kernel<<<dim3((FD * PATCH + 255) / 256), 256, 0, stream>>>(convw, wt);
    encoder_kernel<<<dim3(128, 64), 128, 0, stream>>>(x, wt, feat);
    sample_kernel<<<dim3(1024, 32), 128, 0, stream>>>(feat, aff, fa);

    const dim3 gS(16, 16, 4);      // score GEMM grid (4 blocks/CU)
    const dim3 gG(8, 8, 4);        // 1024^3 GEMM grid
    const int  SMB = 4 * 1024;     // softmax blocks for a 4-mat buffer

    // tm0 = softmax(feat[7] @ feat[8]^T)
    gemm_nt_score<<<gS, 256, 0, stream>>>(
        feat + (size_t)7 * FRAME_ELEMS, sFF,
        feat + (size_t)8 * FRAME_ELEMS, sFF, tm);
    softmax_kernel<<<SMB, 256, 0, stream>>>(tm);

    // scan steps i=0..6:
    //   dst = softmax(f[8+i] @ f[9+i]^T);  tmp = tm @ dst
    //   src = softmax(f[6-i] @ f[7-i]^T);  tm  = src @ tmp   (skip i=6: dead)
    //   al  = softmax(fa[6-i] @ f[7-i]^T); out[6-i] = al @ tmp (skip i=0: dropped)
    for (int i = 0; i < 7; ++i) {
        gemm_nt_score<<<gS, 256, 0, stream>>>(
            feat + (size_t)(8 + i) * FRAME_ELEMS, sFF,
            feat + (size_t)(9 + i) * FRAME_ELEMS, sFF, S);
        softmax_kernel<<<SMB, 256, 0, stream>>>(S);
        gemm_nn128<<<gG, 256, 0, stream>>>(tm, MAT, S, MAT, tmp, MAT);

        if (i < 6) {
            gemm_nt_score<<<gS, 256, 0, stream>>>(
                feat + (size_t)(6 - i) * FRAME_ELEMS, sFF,
                feat + (size_t)(7 - i) * FRAME_ELEMS, sFF, S);
            softmax_kernel<<<SMB, 256, 0, stream>>>(S);
            gemm_nn128<<<gG, 256, 0, stream>>>(S, MAT, tmp, MAT, tm, MAT);
        }
        if (i >= 1) {
            gemm_nt_score<<<gS, 256, 0, stream>>>(
                fa + (size_t)(6 - i) * FRAME_ELEMS, sFA,
                feat + (size_t)(7 - i) * FRAME_ELEMS, sFF, S);
            softmax_kernel<<<SMB, 256, 0, stream>>>(S);
            gemm_nn128<<<gG, 256, 0, stream>>>(
                S, MAT, tmp, MAT, out + (size_t)(6 - i) * 4 * MAT, MAT);
        }
    }
}

// Round 10
// 2037.271 us; speedup vs baseline: 1.7413x; 1.7413x over previous
//
#include <hip/hip_runtime.h>

// Problem constants (B=4, TT=16, T=8, C=3, H=W=256, STRIDE=8, Fd=128, fh=fw=32)
#define FD 128
#define HWP 1024
#define FRAME_ELEMS (HWP * FD)     // 131072 floats per frame (seq layout [pixel][ch])
#define MAT 1048576                 // 1024*1024
#define TEMP_INV 14.285714285714286f
static constexpr int PATCH = 192;   // 3*8*8

typedef __attribute__((ext_vector_type(8))) short short8v;   // 8 bf16 (4 VGPRs)
typedef __attribute__((ext_vector_type(4))) float f32x4;     // MFMA acc frag

// ---------------------------------------------------------------------------
// Kernel 0: transpose conv weights [128][192] -> [192][128] for coalesced reads
// ---------------------------------------------------------------------------
__global__ __launch_bounds__(256) void transpose_w_kernel(
    const float* __restrict__ w, float* __restrict__ wt)
{
    int idx = blockIdx.x * 256 + threadIdx.x;
    if (idx < FD * PATCH) {
        int o = idx / PATCH, k = idx - o * PATCH;
        wt[k * FD + o] = w[idx];
    }
}

// ---------------------------------------------------------------------------
// Kernel 1: patch-embed conv (stride-8 8x8, VALID) + ReLU + channel l2norm.
// ---------------------------------------------------------------------------
__global__ __launch_bounds__(128) void encoder_kernel(
    const float* __restrict__ x, const float* __restrict__ wt,
    float* __restrict__ feat)
{
    const int frame = blockIdx.y;
    const int pg0 = blockIdx.x * 8;
    const int c = threadIdx.x;

    __shared__ float patch[8][PATCH];
    __shared__ float part[8][2];

    for (int idx = c; idx < 8 * PATCH; idx += 128) {
        int p = idx / PATCH, k = idx - p * PATCH;
        int pg = pg0 + p;
        int oy = pg >> 5, ox = pg & 31;
        int ci = k >> 6, r = k & 63;
        int ky = r >> 3, kx = r & 7;
        patch[p][k] = x[(size_t)(((frame * 3 + ci) << 8) + oy * 8 + ky) * 256
                        + ox * 8 + kx];
    }
    __syncthreads();

    float acc[8] = {0.f, 0.f, 0.f, 0.f, 0.f, 0.f, 0.f, 0.f};
    for (int k = 0; k < PATCH; ++k) {
        float wv = wt[k * FD + c];
#pragma unroll
        for (int p = 0; p < 8; ++p) acc[p] = fmaf(wv, patch[p][k], acc[p]);
    }
#pragma unroll
    for (int p = 0; p < 8; ++p) acc[p] = fmaxf(acc[p], 0.f);

    const int lane = c & 63, wid = c >> 6;
#pragma unroll
    for (int p = 0; p < 8; ++p) {
        float s = acc[p] * acc[p];
#pragma unroll
        for (int off = 32; off > 0; off >>= 1) s += __shfl_xor(s, off, 64);
        if (lane == 0) part[p][wid] = s;
    }
    __syncthreads();

    float* out = feat + (size_t)frame * FRAME_ELEMS + (size_t)pg0 * FD + c;
#pragma unroll
    for (int p = 0; p < 8; ++p) {
        float nrm = fmaxf(sqrtf(part[p][0] + part[p][1]), 1e-12f);
        out[(size_t)p * FD] = acc[p] / nrm;
    }
}

// ---------------------------------------------------------------------------
// Kernel 2: affine grid + bilinear grid-sample + channel l2norm.
// ---------------------------------------------------------------------------
__global__ __launch_bounds__(128) void sample_kernel(
    const float* __restrict__ feat, const float* __restrict__ aff,
    float* __restrict__ fa)
{
    const int p = blockIdx.x;
    const int n = blockIdx.y;
    const int c = threadIdx.x;
    const int b = n >> 3, t = n & 7;
    const float* th = aff + b * 6;
    const int oy = p >> 5, ox = p & 31;
    const float xs = -1.f + (2.f / 31.f) * (float)ox;
    const float ys = -1.f + (2.f / 31.f) * (float)oy;
    const float gx = th[0] * xs + th[1] * ys + th[2];
    const float gy = th[3] * xs + th[4] * ys + th[5];
    const float ix = (gx + 1.f) * 0.5f * 31.f;
    const float iy = (gy + 1.f) * 0.5f * 31.f;
    const float x0 = floorf(ix), y0 = floorf(iy);
    const float x1 = x0 + 1.f, y1 = y0 + 1.f;
    const float wx1 = ix - x0, wx0 = 1.f - wx1;
    const float wy1 = iy - y0, wy0 = 1.f - wy1;

    const float* fr = feat + (size_t)(b * 16 + t) * FRAME_ELEMS;

    float yys[4] = {y0, y0, y1, y1};
    float xxs[4] = {x0, x1, x0, x1};
    float wts[4] = {wy0 * wx0, wy0 * wx1, wy1 * wx0, wy1 * wx1};
    float v = 0.f;
#pragma unroll
    for (int q = 0; q < 4; ++q) {
        float yy = yys[q], xx = xxs[q];
        bool inb = (xx >= 0.f) && (xx <= 31.f) && (yy >= 0.f) && (yy <= 31.f);
        int yc = (int)fminf(fmaxf(yy, 0.f), 31.f);
        int xc = (int)fminf(fmaxf(xx, 0.f), 31.f);
        v += fr[(size_t)(yc * 32 + xc) * FD + c] * (inb ? wts[q] : 0.f);
    }

    __shared__ float part[2];
    float s = v * v;
#pragma unroll
    for (int off = 32; off > 0; off >>= 1) s += __shfl_xor(s, off, 64);
    const int lane = c & 63, wid = c >> 6;
    if (lane == 0) part[wid] = s;
    __syncthreads();
    float nrm = fmaxf(sqrtf(part[0] + part[1]), 1e-12f);
    fa[(size_t)n * FRAME_ELEMS + (size_t)p * FD + c] = v / nrm;
}

// ---------------------------------------------------------------------------
// Kernel 3: score GEMM C = X @ Y^T, X,Y 1024x128 row-major. Batched grid.z.
// ---------------------------------------------------------------------------
__global__ __launch_bounds__(256) void gemm_nt_score(
    const float* __restrict__ Xb, int sX,
    const float* __restrict__ Yb, int sY,
    float* __restrict__ Ob)
{
    const float* __restrict__ X = Xb + (size_t)blockIdx.z * (size_t)sX;
    const float* __restrict__ Y = Yb + (size_t)blockIdx.z * (size_t)sY;
    float* __restrict__ C = Ob + (size_t)blockIdx.z * (size_t)MAT;

    __shared__ float Xs[16][68];
    __shared__ float Ys[16][68];
    const int tid = threadIdx.x;
    const int bm = blockIdx.y * 64, bn = blockIdx.x * 64;
    const int tr = tid >> 4, tc = tid & 15;
    const int lm = tid >> 4, lk = tid & 15;
    float acc[4][4] = {};

    for (int k0 = 0; k0 < FD; k0 += 16) {
#pragma unroll
        for (int j = 0; j < 4; ++j)
            Xs[lk][lm + 16 * j] = X[(size_t)(bm + lm + 16 * j) * FD + k0 + lk];
#pragma unroll
        for (int j = 0; j < 4; ++j)
            Ys[lk][lm + 16 * j] = Y[(size_t)(bn + lm + 16 * j) * FD + k0 + lk];
        __syncthreads();
#pragma unroll
        for (int k = 0; k < 16; ++k) {
            float4 a4 = *(const float4*)&Xs[k][4 * tr];
            float4 b4 = *(const float4*)&Ys[k][4 * tc];
            float aa[4] = {a4.x, a4.y, a4.z, a4.w};
            float bb[4] = {b4.x, b4.y, b4.z, b4.w};
#pragma unroll
            for (int i = 0; i < 4; ++i)
#pragma unroll
                for (int j = 0; j < 4; ++j)
                    acc[i][j] = fmaf(aa[i], bb[j], acc[i][j]);
        }
        __syncthreads();
    }
#pragma unroll
    for (int i = 0; i < 4; ++i) {
        float4 st = {acc[i][0], acc[i][1], acc[i][2], acc[i][3]};
        *(float4*)&C[(size_t)(bm + 4 * tr + i) * HWP + bn + 4 * tc] = st;
    }
}

// ---------------------------------------------------------------------------
// Kernel 4: row softmax of s/TEMP, in place. One block per 1024-elem row.
// ---------------------------------------------------------------------------
__global__ __launch_bounds__(256) void softmax_kernel(float* __restrict__ s)
{
    float* __restrict__ r = s + (size_t)blockIdx.x * HWP;
    const int tid = threadIdx.x;
    const int lane = tid & 63, wid = tid >> 6;
    __shared__ float redm[4];
    __shared__ float reds[4];

    float4 v = ((const float4*)r)[tid];
    float m = fmaxf(fmaxf(v.x, v.y), fmaxf(v.z, v.w));
#pragma unroll
    for (int off = 32; off > 0; off >>= 1) m = fmaxf(m, __shfl_xor(m, off, 64));
    if (lane == 0) redm[wid] = m;
    __syncthreads();
    m = fmaxf(fmaxf(redm[0], redm[1]), fmaxf(redm[2], redm[3]));

    float e[4];
    e[0] = expf((v.x - m) * TEMP_INV);
    e[1] = expf((v.y - m) * TEMP_INV);
    e[2] = expf((v.z - m) * TEMP_INV);
    e[3] = expf((v.w - m) * TEMP_INV);
    float ss = e[0] + e[1] + e[2] + e[3];
#pragma unroll
    for (int off = 32; off > 0; off >>= 1) ss += __shfl_xor(ss, off, 64);
    if (lane == 0) reds[wid] = ss;
    __syncthreads();
    float inv = 1.f / (reds[0] + reds[1] + reds[2] + reds[3]);
    float4 o = {e[0] * inv, e[1] * inv, e[2] * inv, e[3] * inv};
    ((float4*)r)[tid] = o;
}

// ---------------------------------------------------------------------------
// v_cvt_pk_bf16_f32: 2 fp32 -> packed 2 bf16 (RNE). No builtin on gfx950.
// low16 = bf16(a), high16 = bf16(b).
// ---------------------------------------------------------------------------
__device__ __forceinline__ unsigned int cvt_pk_bf16(float a, float b)
{
    unsigned int r;
    asm volatile("v_cvt_pk_bf16_f32 %0, %1, %2" : "=v"(r) : "v"(a), "v"(b));
    return r;
}

// ---------------------------------------------------------------------------
// Kernel 5: batched split-bf16 MFMA SGEMM C = A @ B (1024^3, batch grid.z).
// A,B fp32 -> RNE bf16 hi + residual lo in LDS; acc = AhBh + AhBl + AlBh
// (AlBl term ~2^-16 rel, dropped).  128x128 tile, 4 waves (64x64/wave),
// BK=32, mfma_f32_16x16x32_bf16.
// Frag layout (layout "a"): lane l holds row/col (l&15), k = (l>>4)*8 + j
// CONTIGUOUS (matches m92 bf16x8-vec-load ladder; fp8 16x16x32 analog).
// If absmax blows up: switch to stacked k-order by permuting staging col:
//   c(k) = (k<16) ? (k>>2)*8 + (k&3) : ((k-16)>>2)*8 + 4 + (k&3).
// C/D layout (measured m89): col = lane&15, row = (lane>>4)*4 + reg.
// ---------------------------------------------------------------------------
__global__ __launch_bounds__(256) void gemm_nn_mfma(
    const float* __restrict__ Ab, int sA,
    const float* __restrict__ Bb, int sB,
    float* __restrict__ Cb, int sC)
{
    const float* __restrict__ A = Ab + (size_t)blockIdx.z * (size_t)sA;
    const float* __restrict__ B = Bb + (size_t)blockIdx.z * (size_t)sB;
    float* __restrict__ C = Cb + (size_t)blockIdx.z * (size_t)sC;

    // LDS tiles, row stride 40 bf16 (80 B = 5x16B: aligned b128 rows, padded)
    __shared__ __align__(16) unsigned short Ah[128][40];
    __shared__ __align__(16) unsigned short Al[128][40];
    __shared__ __align__(16) unsigned short Bh[128][40];  // transposed [n][k]
    __shared__ __align__(16) unsigned short Bl[128][40];

    const int tid = threadIdx.x;
    const int lane = tid & 63;
    const int w = tid >> 6;                 // wave 0..3
    const int wr = w >> 1, wc = w & 1;      // wave tile (64x64)
    const int lo16 = lane & 15;
    const int kg = lane >> 4;               // k-group 0..3
    const int kg8 = kg * 8;
    const int bm = blockIdx.y * 128, bn = blockIdx.x * 128;

    // staging maps
    const int am = tid >> 1;                // A row 0..127
    const int ac = (tid & 1) * 16;          // A k-seg {0,16}
    const int bkr = tid >> 3;               // B k row 0..31
    const int bn4 = (tid & 7) * 16;         // B n base {0,16,...,112}

    f32x4 acc[4][4] = {};
    float4 pa[4], pb[4];

    // ---- prologue: load tile 0 ----
#pragma unroll
    for (int j = 0; j < 4; ++j) {
        pa[j] = *(const float4*)&A[(size_t)(bm + am) * 1024 + ac + 4 * j];
        pb[j] = *(const float4*)&B[(size_t)bkr * 1024 + bn + bn4 + 4 * j];
    }

    for (int s = 0; s < 32; ++s) {
        // ---- convert + store tile s (regs -> LDS) ----
#pragma unroll
        for (int j = 0; j < 4; ++j) {
            float4 f = pa[j];
            unsigned int hp0 = cvt_pk_bf16(f.x, f.y);
            unsigned int hp1 = cvt_pk_bf16(f.z, f.w);
            float h0 = __uint_as_float(hp0 << 16);
            float h1 = __uint_as_float(hp0 & 0xFFFF0000u);
            float h2 = __uint_as_float(hp1 << 16);
            float h3 = __uint_as_float(hp1 & 0xFFFF0000u);
            unsigned int lp0 = cvt_pk_bf16(f.x - h0, f.y - h1);
            unsigned int lp1 = cvt_pk_bf16(f.z - h2, f.w - h3);
            *(uint2*)&Ah[am][ac + 4 * j] = make_uint2(hp0, hp1);
            *(uint2*)&Al[am][ac + 4 * j] = make_uint2(lp0, lp1);
        }
#pragma unroll
        for (int j = 0; j < 4; ++j) {
            float4 f = pb[j];
            int n = bn4 + 4 * j;
            unsigned int hp0 = cvt_pk_bf16(f.x, f.y);
            unsigned int hp1 = cvt_pk_bf16(f.z, f.w);
            float h0 = __uint_as_float(hp0 << 16);
            float h1 = __uint_as_float(hp0 & 0xFFFF0000u);
            float h2 = __uint_as_float(hp1 << 16);
            float h3 = __uint_as_float(hp1 & 0xFFFF0000u);
            unsigned int lp0 = cvt_pk_bf16(f.x - h0, f.y - h1);
            unsigned int lp1 = cvt_pk_bf16(f.z - h2, f.w - h3);
            Bh[n + 0][bkr] = (unsigned short)hp0;
            Bh[n + 1][bkr] = (unsigned short)(hp0 >> 16);
            Bh[n + 2][bkr] = (unsigned short)hp1;
            Bh[n + 3][bkr] = (unsigned short)(hp1 >> 16);
            Bl[n + 0][bkr] = (unsigned short)lp0;
            Bl[n + 1][bkr] = (unsigned short)(lp0 >> 16);
            Bl[n + 2][bkr] = (unsigned short)lp1;
            Bl[n + 3][bkr] = (unsigned short)(lp1 >> 16);
        }
        __syncthreads();

        // ---- issue next-tile loads (latency hides under MFMA) ----
        if (s < 31) {
            const int k0 = (s + 1) * 32;
#pragma unroll
            for (int j = 0; j < 4; ++j) {
                pa[j] = *(const float4*)&A[(size_t)(bm + am) * 1024 + k0 + ac + 4 * j];
                pb[j] = *(const float4*)&B[(size_t)(k0 + bkr) * 1024 + bn + bn4 + 4 * j];
            }
        }

        // ---- MFMA block: 4x4 frags x 3 split terms ----
        short8v ahv[4], alv[4];
#pragma unroll
        for (int m = 0; m < 4; ++m) {
            const int rr = wr * 64 + m * 16 + lo16;
            ahv[m] = *(const short8v*)&Ah[rr][kg8];
            alv[m] = *(const short8v*)&Al[rr][kg8];
        }
#pragma unroll
        for (int nf = 0; nf < 4; ++nf) {
            const int nn = wc * 64 + nf * 16 + lo16;
            short8v bhv = *(const short8v*)&Bh[nn][kg8];
            short8v blv = *(const short8v*)&Bl[nn][kg8];
#pragma unroll
            for (int m = 0; m < 4; ++m) {
                acc[m][nf] = __builtin_amdgcn_mfma_f32_16x16x32_bf16(
                    ahv[m], bhv, acc[m][nf], 0, 0, 0);
                acc[m][nf] = __builtin_amdgcn_mfma_f32_16x16x32_bf16(
                    ahv[m], blv, acc[m][nf], 0, 0, 0);
                acc[m][nf] = __builtin_amdgcn_mfma_f32_16x16x32_bf16(
                    alv[m], bhv, acc[m][nf], 0, 0, 0);
            }
        }
        __syncthreads();   // done reading LDS; next iter may overwrite
    }

    // ---- epilogue: C write (col = lane&15, row = kg*4 + reg) ----
#pragma unroll
    for (int m = 0; m < 4; ++m) {
#pragma unroll
        for (int nf = 0; nf < 4; ++nf) {
            const int row0 = bm + wr * 64 + m * 16 + kg * 4;
            const int col = bn + wc * 64 + nf * 16 + lo16;
#pragma unroll
            for (int reg = 0; reg < 4; ++reg)
                C[(size_t)(row0 + reg) * 1024 + col] = acc[m][nf][reg];
        }
    }
}

// ---------------------------------------------------------------------------
// Host launch.  JIT-score design (peak ws = 24 MAT + wt ~= 100.8 MB).
// Scan GEMMs now split-bf16 MFMA; everything else unchanged from the
// passing R8 baseline (absmax 7.6e-6) for clean attribution.
// ---------------------------------------------------------------------------
extern "C" void kernel_launch(void* const* d_in, const int* in_sizes, int n_in,
                              void* d_out, int out_size, void* d_ws, size_t ws_size,
                              hipStream_t stream)
{
    const float* x     = (const float*)d_in[0];   // (4,16,3,256,256)
    const float* aff   = (const float*)d_in[1];   // (4,2,3)
    const float* convw = (const float*)d_in[2];   // (128,3,8,8)
    float* out = (float*)d_out;                   // (6,4,1024,1024)
    float* ws  = (float*)d_ws;

    const size_t WS_NEED = ((size_t)24 * MAT + (size_t)FD * PATCH) * sizeof(float);
    if (ws_size < WS_NEED) return;

    float* feat = ws;                         // [ 0,  8) 64 frames
    float* fa   = ws + (size_t)8  * MAT;      // [ 8, 12) 32 warped frames
    float* S    = ws + (size_t)12 * MAT;      // [12, 16) reusable score block
    float* tm   = ws + (size_t)16 * MAT;      // [16, 20) scan carry
    float* tmp  = ws + (size_t)20 * MAT;      // [20, 24) scan temp
    float* wt   = ws + (size_t)24 * MAT;      // transposed conv weights

    const int sFF = 16 * FRAME_ELEMS;
    const int sFA = 8 * FRAME_ELEMS;

    transpose_w_kernel<<<dim3((FD * PATCH + 255) / 256), 256, 0, stream>>>(convw, wt);
    encoder_kernel<<<dim3(128, 64), 128, 0, stream>>>(x, wt, feat);
    sample_kernel<<<dim3(1024, 32), 128, 0, stream>>>(feat, aff, fa);

    const dim3 gS(16, 16, 4);      // score GEMM grid
    const dim3 gG(8, 8, 4);        // 1024^3 MFMA GEMM grid (256 blocks)
    const int  SMB = 4 * 1024;

    gemm_nt_score<<<gS, 256, 0, stream>>>(
        feat + (size_t)7 * FRAME_ELEMS, sFF,
        feat + (size_t)8 * FRAME_ELEMS, sFF, tm);
    softmax_kernel<<<SMB, 256, 0, stream>>>(tm);

    for (int i = 0; i < 7; ++i) {
        gemm_nt_score<<<gS, 256, 0, stream>>>(
            feat + (size_t)(8 + i) * FRAME_ELEMS, sFF,
            feat + (size_t)(9 + i) * FRAME_ELEMS, sFF, S);
        softmax_kernel<<<SMB, 256, 0, stream>>>(S);
        gemm_nn_mfma<<<gG, 256, 0, stream>>>(tm, MAT, S, MAT, tmp, MAT);

        if (i < 6) {
            gemm_nt_score<<<gS, 256, 0, stream>>>(
                feat + (size_t)(6 - i) * FRAME_ELEMS, sFF,
                feat + (size_t)(7 - i) * FRAME_ELEMS, sFF, S);
            softmax_kernel<<<SMB, 256, 0, stream>>>(S);
            gemm_nn_mfma<<<gG, 256, 0, stream>>>(S, MAT, tmp, MAT, tm, MAT);
        }
        if (i >= 1) {
            gemm_nt_score<<<gS, 256, 0, stream>>>(
                fa + (size_t)(6 - i) * FRAME_ELEMS, sFA,
                feat + (size_t)(7 - i) * FRAME_ELEMS, sFF, S);
            softmax_kernel<<<SMB, 256, 0, stream>>>(S);
            gemm_nn_mfma<<<gG, 256, 0, stream>>>(
                S, MAT, tmp, MAT, out + (size_t)(6 - i) * 4 * MAT, MAT);
        }
    }
}

// Round 11
// 1416.586 us; speedup vs baseline: 2.5042x; 1.4382x over previous
//
#include <hip/hip_runtime.h>

// Problem constants (B=4, TT=16, T=8, C=3, H=W=256, STRIDE=8, Fd=128, fh=fw=32)
#define FD 128
#define HWP 1024
#define FRAME_ELEMS (HWP * FD)     // 131072 elems per frame
#define MAT 1048576                 // 1024*1024
#define TEMP_INV 14.285714285714286f
static constexpr int PATCH = 192;   // 3*8*8

typedef unsigned short u16;
typedef __attribute__((ext_vector_type(8))) short short8v;   // 8 bf16 (4 VGPRs)
typedef __attribute__((ext_vector_type(4))) float f32x4;     // MFMA acc frag

// RNE fp32 -> bf16 (scalar bit-ops; per learn_hip m240 compiler handles this
// better than hand-written v_cvt_pk asm)
__device__ __forceinline__ u16 f2bf(float x)
{
    union { float f; unsigned u; } a; a.f = x;
    unsigned r = a.u + 0x7FFFu + ((a.u >> 16) & 1u);
    return (u16)(r >> 16);
}
__device__ __forceinline__ float bf2f(u16 h)
{
    union { unsigned u; float f; } a; a.u = ((unsigned)h) << 16;
    return a.f;
}
// split x into hi (RNE bf16) and lo (RNE bf16 of residual)
__device__ __forceinline__ void split_bf(float x, u16& hi, u16& lo)
{
    hi = f2bf(x);
    lo = f2bf(x - bf2f(hi));
}

// ---------------------------------------------------------------------------
// Kernel 0: transpose conv weights [128][192] -> [192][128]
// ---------------------------------------------------------------------------
__global__ __launch_bounds__(256) void transpose_w_kernel(
    const float* __restrict__ w, float* __restrict__ wt)
{
    int idx = blockIdx.x * 256 + threadIdx.x;
    if (idx < FD * PATCH) {
        int o = idx / PATCH, k = idx - o * PATCH;
        wt[k * FD + o] = w[idx];
    }
}

// ---------------------------------------------------------------------------
// Kernel 1: patch conv + ReLU + l2norm. Emits fp32 feat (for sampling) and
// bf16 hi/lo featH/featL (for MFMA score GEMMs).
// ---------------------------------------------------------------------------
__global__ __launch_bounds__(128) void encoder_kernel(
    const float* __restrict__ x, const float* __restrict__ wt,
    float* __restrict__ feat, u16* __restrict__ featH, u16* __restrict__ featL)
{
    const int frame = blockIdx.y;
    const int pg0 = blockIdx.x * 8;
    const int c = threadIdx.x;

    __shared__ float patch[8][PATCH];
    __shared__ float part[8][2];

    for (int idx = c; idx < 8 * PATCH; idx += 128) {
        int p = idx / PATCH, k = idx - p * PATCH;
        int pg = pg0 + p;
        int oy = pg >> 5, ox = pg & 31;
        int ci = k >> 6, r = k & 63;
        int ky = r >> 3, kx = r & 7;
        patch[p][k] = x[(size_t)(((frame * 3 + ci) << 8) + oy * 8 + ky) * 256
                        + ox * 8 + kx];
    }
    __syncthreads();

    float acc[8] = {0.f, 0.f, 0.f, 0.f, 0.f, 0.f, 0.f, 0.f};
    for (int k = 0; k < PATCH; ++k) {
        float wv = wt[k * FD + c];
#pragma unroll
        for (int p = 0; p < 8; ++p) acc[p] = fmaf(wv, patch[p][k], acc[p]);
    }
#pragma unroll
    for (int p = 0; p < 8; ++p) acc[p] = fmaxf(acc[p], 0.f);

    const int lane = c & 63, wid = c >> 6;
#pragma unroll
    for (int p = 0; p < 8; ++p) {
        float s = acc[p] * acc[p];
#pragma unroll
        for (int off = 32; off > 0; off >>= 1) s += __shfl_xor(s, off, 64);
        if (lane == 0) part[p][wid] = s;
    }
    __syncthreads();

    const size_t base = (size_t)frame * FRAME_ELEMS + (size_t)pg0 * FD + c;
#pragma unroll
    for (int p = 0; p < 8; ++p) {
        float nrm = fmaxf(sqrtf(part[p][0] + part[p][1]), 1e-12f);
        float v = acc[p] / nrm;
        feat[base + (size_t)p * FD] = v;
        u16 hi, lo; split_bf(v, hi, lo);
        featH[base + (size_t)p * FD] = hi;
        featL[base + (size_t)p * FD] = lo;
    }
}

// ---------------------------------------------------------------------------
// Kernel 2: grid-sample + l2norm. Emits bf16 hi/lo only.
// ---------------------------------------------------------------------------
__global__ __launch_bounds__(128) void sample_kernel(
    const float* __restrict__ feat, const float* __restrict__ aff,
    u16* __restrict__ faH, u16* __restrict__ faL)
{
    const int p = blockIdx.x;
    const int n = blockIdx.y;
    const int c = threadIdx.x;
    const int b = n >> 3, t = n & 7;
    const float* th = aff + b * 6;
    const int oy = p >> 5, ox = p & 31;
    const float xs = -1.f + (2.f / 31.f) * (float)ox;
    const float ys = -1.f + (2.f / 31.f) * (float)oy;
    const float gx = th[0] * xs + th[1] * ys + th[2];
    const float gy = th[3] * xs + th[4] * ys + th[5];
    const float ix = (gx + 1.f) * 0.5f * 31.f;
    const float iy = (gy + 1.f) * 0.5f * 31.f;
    const float x0 = floorf(ix), y0 = floorf(iy);
    const float x1 = x0 + 1.f, y1 = y0 + 1.f;
    const float wx1 = ix - x0, wx0 = 1.f - wx1;
    const float wy1 = iy - y0, wy0 = 1.f - wy1;

    const float* fr = feat + (size_t)(b * 16 + t) * FRAME_ELEMS;

    float yys[4] = {y0, y0, y1, y1};
    float xxs[4] = {x0, x1, x0, x1};
    float wts[4] = {wy0 * wx0, wy0 * wx1, wy1 * wx0, wy1 * wx1};
    float v = 0.f;
#pragma unroll
    for (int q = 0; q < 4; ++q) {
        float yy = yys[q], xx = xxs[q];
        bool inb = (xx >= 0.f) && (xx <= 31.f) && (yy >= 0.f) && (yy <= 31.f);
        int yc = (int)fminf(fmaxf(yy, 0.f), 31.f);
        int xc = (int)fminf(fmaxf(xx, 0.f), 31.f);
        v += fr[(size_t)(yc * 32 + xc) * FD + c] * (inb ? wts[q] : 0.f);
    }

    __shared__ float part[2];
    float s = v * v;
#pragma unroll
    for (int off = 32; off > 0; off >>= 1) s += __shfl_xor(s, off, 64);
    const int lane = c & 63, wid = c >> 6;
    if (lane == 0) part[wid] = s;
    __syncthreads();
    float nrm = fmaxf(sqrtf(part[0] + part[1]), 1e-12f);
    float o = v / nrm;
    u16 hi, lo; split_bf(o, hi, lo);
    const size_t idx = (size_t)n * FRAME_ELEMS + (size_t)p * FD + c;
    faH[idx] = hi;
    faL[idx] = lo;
}

// ---------------------------------------------------------------------------
// Kernel 3: 4-term split-bf16 MFMA NT score GEMM: C = X @ Y^T (fp32 out).
// X,Y: 1024 rows x 128 k, row stride 128 (u16), hi/lo pairs. Batched grid.z.
// 64x64 tile, 4 waves (32x32 each), BK=32, K=128 (4 steps).
// Frag/D layouts identical to R10's hardware-validated kernel.
// ---------------------------------------------------------------------------
__global__ __launch_bounds__(256) void gemm_nt_mfma4(
    const u16* __restrict__ XH, const u16* __restrict__ XL, long long xBatch,
    const u16* __restrict__ YH, const u16* __restrict__ YL, long long yBatch,
    float* __restrict__ Cb, long long cBatch)
{
    const u16* __restrict__ Xh = XH + (size_t)blockIdx.z * xBatch;
    const u16* __restrict__ Xl = XL + (size_t)blockIdx.z * xBatch;
    const u16* __restrict__ Yh = YH + (size_t)blockIdx.z * yBatch;
    const u16* __restrict__ Yl = YL + (size_t)blockIdx.z * yBatch;
    float* __restrict__ C = Cb + (size_t)blockIdx.z * cBatch;

    __shared__ __align__(16) u16 sXh[64][40];
    __shared__ __align__(16) u16 sXl[64][40];
    __shared__ __align__(16) u16 sYh[64][40];
    __shared__ __align__(16) u16 sYl[64][40];

    const int tid = threadIdx.x;
    const int lane = tid & 63;
    const int w = tid >> 6;
    const int wm = w >> 1, wn = w & 1;      // wave sub-tile 32x32
    const int lo16 = lane & 15;
    const int kg = lane >> 4;
    const int kg8 = kg * 8;
    const int bm = blockIdx.y * 64, bn = blockIdx.x * 64;

    const int srow = tid >> 2;              // 0..63
    const int sk = (tid & 3) * 8;           // {0,8,16,24}

    f32x4 acc[2][2] = {};

    for (int k0 = 0; k0 < FD; k0 += 32) {
        *(short8v*)&sXh[srow][sk] =
            *(const short8v*)&Xh[(size_t)(bm + srow) * FD + k0 + sk];
        *(short8v*)&sXl[srow][sk] =
            *(const short8v*)&Xl[(size_t)(bm + srow) * FD + k0 + sk];
        *(short8v*)&sYh[srow][sk] =
            *(const short8v*)&Yh[(size_t)(bn + srow) * FD + k0 + sk];
        *(short8v*)&sYl[srow][sk] =
            *(const short8v*)&Yl[(size_t)(bn + srow) * FD + k0 + sk];
        __syncthreads();

#pragma unroll
        for (int mf = 0; mf < 2; ++mf) {
            const int ar = wm * 32 + mf * 16 + lo16;
            short8v ah = *(const short8v*)&sXh[ar][kg8];
            short8v al = *(const short8v*)&sXl[ar][kg8];
#pragma unroll
            for (int nf = 0; nf < 2; ++nf) {
                const int br = wn * 32 + nf * 16 + lo16;
                short8v bh = *(const short8v*)&sYh[br][kg8];
                short8v bl = *(const short8v*)&sYl[br][kg8];
                acc[mf][nf] = __builtin_amdgcn_mfma_f32_16x16x32_bf16(
                    ah, bh, acc[mf][nf], 0, 0, 0);
                acc[mf][nf] = __builtin_amdgcn_mfma_f32_16x16x32_bf16(
                    ah, bl, acc[mf][nf], 0, 0, 0);
                acc[mf][nf] = __builtin_amdgcn_mfma_f32_16x16x32_bf16(
                    al, bh, acc[mf][nf], 0, 0, 0);
                acc[mf][nf] = __builtin_amdgcn_mfma_f32_16x16x32_bf16(
                    al, bl, acc[mf][nf], 0, 0, 0);
            }
        }
        __syncthreads();
    }

    // D layout (validated R10): col = lane&15, row = kg*4 + reg
#pragma unroll
    for (int mf = 0; mf < 2; ++mf)
#pragma unroll
        for (int nf = 0; nf < 2; ++nf) {
            const int row0 = bm + wm * 32 + mf * 16 + kg * 4;
            const int col = bn + wn * 32 + nf * 16 + lo16;
#pragma unroll
            for (int r = 0; r < 4; ++r)
                C[(size_t)(row0 + r) * HWP + col] = acc[mf][nf][r];
        }
}

// ---------------------------------------------------------------------------
// Kernel 4: row softmax of fp32 scores -> bf16 hi/lo (possibly in-place over
// the fp32 row: all reads happen before the first barrier -> race-free).
// grid = 4*1024 blocks, one per row; block 256.
// ---------------------------------------------------------------------------
__global__ __launch_bounds__(256) void softmax_bf(
    const float* __restrict__ src, long long sBatch,
    u16* __restrict__ dH, u16* __restrict__ dL, int dRow, long long dBatch)
{
    const int mat = blockIdx.x >> 10;
    const int row = blockIdx.x & 1023;
    const float* __restrict__ r = src + (size_t)mat * sBatch + (size_t)row * HWP;
    const int tid = threadIdx.x;
    const int lane = tid & 63, wid = tid >> 6;
    __shared__ float redm[4];
    __shared__ float reds[4];

    float4 v = ((const float4*)r)[tid];
    float m = fmaxf(fmaxf(v.x, v.y), fmaxf(v.z, v.w));
#pragma unroll
    for (int off = 32; off > 0; off >>= 1) m = fmaxf(m, __shfl_xor(m, off, 64));
    if (lane == 0) redm[wid] = m;
    __syncthreads();
    m = fmaxf(fmaxf(redm[0], redm[1]), fmaxf(redm[2], redm[3]));

    float e[4];
    e[0] = expf((v.x - m) * TEMP_INV);
    e[1] = expf((v.y - m) * TEMP_INV);
    e[2] = expf((v.z - m) * TEMP_INV);
    e[3] = expf((v.w - m) * TEMP_INV);
    float ss = e[0] + e[1] + e[2] + e[3];
#pragma unroll
    for (int off = 32; off > 0; off >>= 1) ss += __shfl_xor(ss, off, 64);
    if (lane == 0) reds[wid] = ss;
    __syncthreads();
    float inv = 1.f / (reds[0] + reds[1] + reds[2] + reds[3]);

    ushort4 oh, ol;
    u16 hi, lo;
    split_bf(e[0] * inv, hi, lo); oh.x = hi; ol.x = lo;
    split_bf(e[1] * inv, hi, lo); oh.y = hi; ol.y = lo;
    split_bf(e[2] * inv, hi, lo); oh.z = hi; ol.z = lo;
    split_bf(e[3] * inv, hi, lo); oh.w = hi; ol.w = lo;

    u16* __restrict__ ph = dH + (size_t)mat * dBatch + (size_t)row * dRow;
    u16* __restrict__ pl = dL + (size_t)mat * dBatch + (size_t)row * dRow;
    ((ushort4*)ph)[tid] = oh;
    ((ushort4*)pl)[tid] = ol;
}

// swizzle for scan-GEMM B-tile LDS (breaks ds_write_b16 8-way conflict)
__device__ __forceinline__ int bswz(int n, int k)
{
    return k ^ (((n >> 3) & 3) << 3);
}

// ---------------------------------------------------------------------------
// Kernel 5: 3-term split-bf16 MFMA NN GEMM: C = A @ B (1024^3, batch grid.z).
// A row-major [m][k] (stride aRow), B row-major [k][n] (stride bRow); B is
// transpose-staged in LDS (swizzled). 128x64 tile, 4 waves (64x32 each),
// BK=32. grid (16,8,4) = 512 blocks = 2 blocks/CU.
// emitF32: write fp32 C; else write bf16 hi/lo (for chained consumption).
// 3-term accuracy validated on HW in R10 (absmax unchanged vs fp32).
// ---------------------------------------------------------------------------
__global__ __launch_bounds__(256) void gemm_nn_mfma3(
    const u16* __restrict__ AH, const u16* __restrict__ AL,
    int aRow, long long aBatch,
    const u16* __restrict__ BH, const u16* __restrict__ BL,
    int bRow, long long bBatch,
    int emitF32, float* __restrict__ Cf, long long cfBatch,
    u16* __restrict__ CH, u16* __restrict__ CL, long long cBatch)
{
    const u16* __restrict__ Ah = AH + (size_t)blockIdx.z * aBatch;
    const u16* __restrict__ Al = AL + (size_t)blockIdx.z * aBatch;
    const u16* __restrict__ Bh = BH + (size_t)blockIdx.z * bBatch;
    const u16* __restrict__ Bl = BL + (size_t)blockIdx.z * bBatch;

    __shared__ __align__(16) u16 sAh[128][40];
    __shared__ __align__(16) u16 sAl[128][40];
    __shared__ __align__(16) u16 sBh[64][40];   // [n][k] swizzled
    __shared__ __align__(16) u16 sBl[64][40];

    const int tid = threadIdx.x;
    const int lane = tid & 63;
    const int w = tid >> 6;
    const int wm = w >> 1, wn = w & 1;       // wave sub-tile 64x32
    const int lo16 = lane & 15;
    const int kg = lane >> 4;
    const int kg8 = kg * 8;
    const int bm = blockIdx.y * 128, bn = blockIdx.x * 64;

    // staging maps
    const int arow0 = tid >> 1;              // A row 0..127
    const int ak = (tid & 1) * 16;           // A k half {0,16}
    const int bk = tid >> 3;                 // B k row 0..31
    const int bn8 = (tid & 7) * 8;           // B n base {0..56}

    f32x4 acc[4][2] = {};

    for (int k0 = 0; k0 < 1024; k0 += 32) {
        // A: direct copy (hi/lo), 2x short8 per plane
        *(short8v*)&sAh[arow0][ak] =
            *(const short8v*)&Ah[(size_t)(bm + arow0) * aRow + k0 + ak];
        *(short8v*)&sAh[arow0][ak + 8] =
            *(const short8v*)&Ah[(size_t)(bm + arow0) * aRow + k0 + ak + 8];
        *(short8v*)&sAl[arow0][ak] =
            *(const short8v*)&Al[(size_t)(bm + arow0) * aRow + k0 + ak];
        *(short8v*)&sAl[arow0][ak + 8] =
            *(const short8v*)&Al[(size_t)(bm + arow0) * aRow + k0 + ak + 8];
        // B: load row-chunk, transpose-store swizzled
        {
            short8v vh = *(const short8v*)&Bh[(size_t)(k0 + bk) * bRow + bn + bn8];
            short8v vl = *(const short8v*)&Bl[(size_t)(k0 + bk) * bRow + bn + bn8];
#pragma unroll
            for (int j = 0; j < 8; ++j) {
                sBh[bn8 + j][bswz(bn8 + j, bk)] = (u16)vh[j];
                sBl[bn8 + j][bswz(bn8 + j, bk)] = (u16)vl[j];
            }
        }
        __syncthreads();

        short8v ah[4], al[4];
#pragma unroll
        for (int mf = 0; mf < 4; ++mf) {
            const int ar = wm * 64 + mf * 16 + lo16;
            ah[mf] = *(const short8v*)&sAh[ar][kg8];
            al[mf] = *(const short8v*)&sAl[ar][kg8];
        }
#pragma unroll
        for (int nf = 0; nf < 2; ++nf) {
            const int br = wn * 32 + nf * 16 + lo16;
            const int kk = bswz(br, kg8);
            short8v bh = *(const short8v*)&sBh[br][kk];
            short8v bl = *(const short8v*)&sBl[br][kk];
#pragma unroll
            for (int mf = 0; mf < 4; ++mf) {
                acc[mf][nf] = __builtin_amdgcn_mfma_f32_16x16x32_bf16(
                    ah[mf], bh, acc[mf][nf], 0, 0, 0);
                acc[mf][nf] = __builtin_amdgcn_mfma_f32_16x16x32_bf16(
                    ah[mf], bl, acc[mf][nf], 0, 0, 0);
                acc[mf][nf] = __builtin_amdgcn_mfma_f32_16x16x32_bf16(
                    al[mf], bh, acc[mf][nf], 0, 0, 0);
            }
        }
        __syncthreads();
    }

    // D layout (validated R10): col = lane&15, row = kg*4 + reg
    if (emitF32) {
        float* __restrict__ C = Cf + (size_t)blockIdx.z * cfBatch;
#pragma unroll
        for (int mf = 0; mf < 4; ++mf)
#pragma unroll
            for (int nf = 0; nf < 2; ++nf) {
                const int row0 = bm + wm * 64 + mf * 16 + kg * 4;
                const int col = bn + wn * 32 + nf * 16 + lo16;
#pragma unroll
                for (int r = 0; r < 4; ++r)
                    C[(size_t)(row0 + r) * HWP + col] = acc[mf][nf][r];
            }
    } else {
        u16* __restrict__ Ch = CH + (size_t)blockIdx.z * cBatch;
        u16* __restrict__ Cl = CL + (size_t)blockIdx.z * cBatch;
#pragma unroll
        for (int mf = 0; mf < 4; ++mf)
#pragma unroll
            for (int nf = 0; nf < 2; ++nf) {
                const int row0 = bm + wm * 64 + mf * 16 + kg * 4;
                const int col = bn + wn * 32 + nf * 16 + lo16;
#pragma unroll
                for (int r = 0; r < 4; ++r) {
                    u16 hi, lo; split_bf(acc[mf][nf][r], hi, lo);
                    Ch[(size_t)(row0 + r) * HWP + col] = hi;
                    Cl[(size_t)(row0 + r) * HWP + col] = lo;
                }
            }
    }
}

// ---------------------------------------------------------------------------
// Host launch. All-MFMA pipeline with bf16 hi/lo materialized operands.
// Workspace (bytes, total = 96MB + wt = identical to the R8-proven guard):
//   [0,32MB)  feat fp32 (dead after sample) -> tmH/tmL/tmpH/tmpL (8MB each)
//   [32,48)   featH   [48,64) featL
//   [64,72)   faH     [72,80) faL
//   [80,96)   S: fp32 scores, softmax'd IN PLACE to hi(1024u16)+lo per 4KB row
//   [96, +96KB) wt
// ---------------------------------------------------------------------------
extern "C" void kernel_launch(void* const* d_in, const int* in_sizes, int n_in,
                              void* d_out, int out_size, void* d_ws, size_t ws_size,
                              hipStream_t stream)
{
    const float* x     = (const float*)d_in[0];
    const float* aff   = (const float*)d_in[1];
    const float* convw = (const float*)d_in[2];
    float* out = (float*)d_out;

    const size_t MB = 1u << 20;
    unsigned char* wsb = (unsigned char*)d_ws;

    const size_t WS_NEED = ((size_t)24 * MAT + (size_t)FD * PATCH) * sizeof(float);
    if (ws_size < WS_NEED) return;

    float* feat  = (float*)(wsb);
    u16* tmH     = (u16*)(wsb);
    u16* tmL     = (u16*)(wsb + 8 * MB);
    u16* tmpH    = (u16*)(wsb + 16 * MB);
    u16* tmpL    = (u16*)(wsb + 24 * MB);
    u16* featH   = (u16*)(wsb + 32 * MB);
    u16* featL   = (u16*)(wsb + 48 * MB);
    u16* faH     = (u16*)(wsb + 64 * MB);
    u16* faL     = (u16*)(wsb + 72 * MB);
    float* S     = (float*)(wsb + 80 * MB);
    u16* SH      = (u16*)S;            // in-place: row r hi at r*2048, lo +1024
    u16* SL      = SH + 1024;
    float* wt    = (float*)(wsb + 96 * MB);

    const long long fB  = 16LL * FRAME_ELEMS;  // feat batch stride (u16 elems)
    const long long faB = 8LL * FRAME_ELEMS;
    const long long S_F = 1LL * MAT;           // S fp32 batch stride (floats)
    const long long S_U = 2LL * MAT;           // S hi/lo batch stride (u16)
    const long long T_U = 1LL * MAT;           // tm/tmp batch stride (u16)

    transpose_w_kernel<<<dim3((FD * PATCH + 255) / 256), 256, 0, stream>>>(convw, wt);
    encoder_kernel<<<dim3(128, 64), 128, 0, stream>>>(x, wt, feat, featH, featL);
    sample_kernel<<<dim3(1024, 32), 128, 0, stream>>>(feat, aff, faH, faL);

    const dim3 gS(16, 16, 4);   // score NT MFMA grid (1024 blocks, 4/CU)
    const dim3 gG(16, 8, 4);    // scan NN MFMA grid (512 blocks, 2/CU)
    const int  SMB = 4 * 1024;

    // tm0 = softmax(f7 @ f8^T) -> tmH/tmL
    gemm_nt_mfma4<<<gS, 256, 0, stream>>>(
        featH + (size_t)7 * FRAME_ELEMS, featL + (size_t)7 * FRAME_ELEMS, fB,
        featH + (size_t)8 * FRAME_ELEMS, featL + (size_t)8 * FRAME_ELEMS, fB,
        S, S_F);
    softmax_bf<<<SMB, 256, 0, stream>>>(S, S_F, tmH, tmL, 1024, T_U);

    for (int i = 0; i < 7; ++i) {
        // dst = softmax(f[8+i] @ f[9+i]^T), in-place hi/lo; tmp = tm @ dst
        gemm_nt_mfma4<<<gS, 256, 0, stream>>>(
            featH + (size_t)(8 + i) * FRAME_ELEMS,
            featL + (size_t)(8 + i) * FRAME_ELEMS, fB,
            featH + (size_t)(9 + i) * FRAME_ELEMS,
            featL + (size_t)(9 + i) * FRAME_ELEMS, fB, S, S_F);
        softmax_bf<<<SMB, 256, 0, stream>>>(S, S_F, SH, SL, 2048, S_U);
        gemm_nn_mfma3<<<gG, 256, 0, stream>>>(
            tmH, tmL, 1024, T_U, SH, SL, 2048, S_U,
            0, nullptr, 0, tmpH, tmpL, T_U);

        if (i < 6) {  // src = softmax(f[6-i] @ f[7-i]^T); tm = src @ tmp
            gemm_nt_mfma4<<<gS, 256, 0, stream>>>(
                featH + (size_t)(6 - i) * FRAME_ELEMS,
                featL + (size_t)(6 - i) * FRAME_ELEMS, fB,
                featH + (size_t)(7 - i) * FRAME_ELEMS,
                featL + (size_t)(7 - i) * FRAME_ELEMS, fB, S, S_F);
            softmax_bf<<<SMB, 256, 0, stream>>>(S, S_F, SH, SL, 2048, S_U);
            gemm_nn_mfma3<<<gG, 256, 0, stream>>>(
                SH, SL, 2048, S_U, tmpH, tmpL, 1024, T_U,
                0, nullptr, 0, tmH, tmL, T_U);
        }
        if (i >= 1) { // al = softmax(fa[6-i] @ f[7-i]^T); out[6-i] = al @ tmp
            gemm_nt_mfma4<<<gS, 256, 0, stream>>>(
                faH + (size_t)(6 - i) * FRAME_ELEMS,
                faL + (size_t)(6 - i) * FRAME_ELEMS, faB,
                featH + (size_t)(7 - i) * FRAME_ELEMS,
                featL + (size_t)(7 - i) * FRAME_ELEMS, fB, S, S_F);
            softmax_bf<<<SMB, 256, 0, stream>>>(S, S_F, SH, SL, 2048, S_U);
            gemm_nn_mfma3<<<gG, 256, 0, stream>>>(
                SH, SL, 2048, S_U, tmpH, tmpL, 1024, T_U,
                1, out + (size_t)(6 - i) * 4 * MAT, (long long)MAT,
                nullptr, nullptr, 0);
        }
    }
}